// Round 4
// baseline (112.911 us; speedup 1.0000x reference)
//
#include <hip/hip_runtime.h>
#include <math.h>

static constexpr int B_  = 4;
static constexpr int TQ  = 128;
static constexpr int TK  = 512;
static constexpr int NN  = 1024;
static constexpr int QS  = 1024;
static constexpr int VS  = 1024;
static constexpr int OS  = 1024;

#define K2F    2.8853900817779268f   // 2*log2(e)
#define LOG2EF 1.4426950408889634f

typedef __attribute__((ext_vector_type(8))) short bf16x8;
typedef __attribute__((ext_vector_type(4))) float f32x4;

#define MFMA16(a,b,c) __builtin_amdgcn_mfma_f32_16x16x32_bf16((a),(b),(c),0,0,0)

// f32 -> bf16 round-to-nearest-even
__device__ __forceinline__ ushort bf16_rne(float x) {
    uint u = __float_as_uint(x);
    u += 0x7FFFu + ((u >> 16) & 1u);
    return (ushort)(u >> 16);
}
// split f32 into hi+lo bf16 (a ~= hi + lo, rel err ~2^-17)
__device__ __forceinline__ void split2(float x, ushort& h, ushort& l) {
    ushort hh = bf16_rne(x);
    float hv = __uint_as_float((uint)hh << 16);
    h = hh;
    l = bf16_rne(x - hv);
}

// ---------------------------------------------------------------------------
// [1] fused conversion: Q (512 blk), Wq (1024 blk), Wout (2048 blk) -> hi/lo
// ---------------------------------------------------------------------------
__global__ __launch_bounds__(256) void cvt_fused_kernel(
    const float* __restrict__ Q, const float* __restrict__ Wq,
    const float* __restrict__ Wo,
    ushort* __restrict__ Qh, ushort* __restrict__ Ql,
    ushort* __restrict__ Wqh, ushort* __restrict__ Wql,
    ushort* __restrict__ Woh, ushort* __restrict__ Wol)
{
    int bid = blockIdx.x;
    const float* src; ushort *h, *l; int idx;
    if (bid < 512)       { src = Q;  h = Qh;  l = Ql;  idx = bid*256 + threadIdx.x; }
    else if (bid < 1536) { src = Wq; h = Wqh; l = Wql; idx = (bid-512)*256 + threadIdx.x; }
    else                 { src = Wo; h = Woh; l = Wol; idx = (bid-1536)*256 + threadIdx.x; }
    float4 v = ((const float4*)src)[idx];
    ushort4 hh, ll;
    split2(v.x, hh.x, ll.x); split2(v.y, hh.y, ll.y);
    split2(v.z, hh.z, ll.z); split2(v.w, hh.w, ll.w);
    ((ushort4*)h)[idx] = hh;
    ((ushort4*)l)[idx] = ll;
}

// ---------------------------------------------------------------------------
// [2] V [b][k=512][v=1024] -> Vt hi/lo [b][v=1024][k=512]
// ---------------------------------------------------------------------------
__global__ __launch_bounds__(256) void cvt_transpose_v_kernel(
    const float* __restrict__ V, ushort* __restrict__ Th, ushort* __restrict__ Tl)
{
    __shared__ float tile[64][65];
    const int b = blockIdx.z, k0 = blockIdx.y * 64, v0 = blockIdx.x * 64;
    const int t = threadIdx.x;
    const float* src = V + ((size_t)b*TK + k0)*VS + v0;
    #pragma unroll
    for (int p = 0; p < 4; ++p) {
        int r = (t >> 4) + p*16, c = (t & 15) * 4;
        float4 vv = *(const float4*)(src + (size_t)r*VS + c);
        tile[r][c] = vv.x; tile[r][c+1] = vv.y; tile[r][c+2] = vv.z; tile[r][c+3] = vv.w;
    }
    __syncthreads();
    ushort* dh = Th + (size_t)b*(VS*TK) + (size_t)v0*TK + k0;
    ushort* dl = Tl + (size_t)b*(VS*TK) + (size_t)v0*TK + k0;
    #pragma unroll
    for (int p = 0; p < 4; ++p) {
        int vr = (t >> 4) + p*16, kc = (t & 15) * 4;
        ushort4 hh, ll;
        split2(tile[kc+0][vr], hh.x, ll.x);
        split2(tile[kc+1][vr], hh.y, ll.y);
        split2(tile[kc+2][vr], hh.z, ll.z);
        split2(tile[kc+3][vr], hh.w, ll.w);
        *(ushort4*)(dh + (size_t)vr*TK + kc) = hh;
        *(ushort4*)(dl + (size_t)vr*TK + kc) = ll;
    }
}

// ---------------------------------------------------------------------------
// shared MFMA main loop: 32(M) x 64(N) block tile, 4 waves x (16x32),
// split-bf16 3-MFMA emulation, NT layout (B rows = output cols).
// lA: [2][32][40] ushort, lB: [2][64][40] ushort (flat).
// ---------------------------------------------------------------------------
__device__ __forceinline__ void mfma_core(
    const ushort* __restrict__ Ah, const ushort* __restrict__ Al, int lda,
    const ushort* __restrict__ Bh, const ushort* __restrict__ Bl, int ldb,
    int K, int m0, int n0,
    ushort* lA, ushort* lB, f32x4& acc0, f32x4& acc1)
{
    const int t = threadIdx.x;
    const int a_hl = t >> 7, a_row = (t >> 2) & 31, a_kc = (t & 3) * 8;
    const int b_row = t >> 2, b_kc = (t & 3) * 8;
    const int lane = t & 63, w = t >> 6;
    const int wm = (w & 1) * 16, wn = (w >> 1) * 32;
    const int fr = lane & 15, fg = (lane >> 4) * 8;
    const ushort* aptr = (a_hl ? Al : Ah) + (size_t)(m0 + a_row) * lda + a_kc;
    const ushort* bhp  = Bh + (size_t)(n0 + b_row) * ldb + b_kc;
    const ushort* blp  = Bl + (size_t)(n0 + b_row) * ldb + b_kc;
    ushort* lAw = lA + (a_hl*32 + a_row)*40 + a_kc;
    ushort* lB0 = lB + b_row*40 + b_kc;
    ushort* lB1 = lB + (64 + b_row)*40 + b_kc;
    const ushort* rAh  = lA + (wm + fr)*40 + fg;
    const ushort* rAl  = lA + (32 + wm + fr)*40 + fg;
    const ushort* rB0h = lB + (wn + fr)*40 + fg;
    const ushort* rB1h = lB + (wn + 16 + fr)*40 + fg;
    const ushort* rB0l = lB + (64 + wn + fr)*40 + fg;
    const ushort* rB1l = lB + (64 + wn + 16 + fr)*40 + fg;
    for (int kb = 0; kb < K; kb += 32) {
        *(uint4*)lAw = *(const uint4*)(aptr + kb);
        *(uint4*)lB0 = *(const uint4*)(bhp + kb);
        *(uint4*)lB1 = *(const uint4*)(blp + kb);
        __syncthreads();
        bf16x8 ah  = *(const bf16x8*)rAh;
        bf16x8 al  = *(const bf16x8*)rAl;
        bf16x8 bh0 = *(const bf16x8*)rB0h;
        bf16x8 bh1 = *(const bf16x8*)rB1h;
        bf16x8 bl0 = *(const bf16x8*)rB0l;
        bf16x8 bl1 = *(const bf16x8*)rB1l;
        acc0 = MFMA16(ah, bh0, acc0);
        acc0 = MFMA16(al, bh0, acc0);
        acc0 = MFMA16(ah, bl0, acc0);
        acc1 = MFMA16(ah, bh1, acc1);
        acc1 = MFMA16(al, bh1, acc1);
        acc1 = MFMA16(ah, bl1, acc1);
        __syncthreads();
    }
}

// ---------------------------------------------------------------------------
// [3] Ea = exp2((Q@Wq^T + bq) * 2log2e), fused epilogue
// ---------------------------------------------------------------------------
__global__ __launch_bounds__(256) void mfma_a_exp_kernel(
    const ushort* __restrict__ Qh, const ushort* __restrict__ Ql,
    const ushort* __restrict__ Wqh, const ushort* __restrict__ Wql,
    const float* __restrict__ bq, float* __restrict__ Ea)
{
    __shared__ alignas(16) ushort lA[2*32*40];
    __shared__ alignas(16) ushort lB[2*64*40];
    const int m0 = blockIdx.y*32, n0 = blockIdx.x*64;
    f32x4 acc0 = {0,0,0,0}, acc1 = {0,0,0,0};
    mfma_core(Qh, Ql, 1024, Wqh, Wql, 1024, 1024, m0, n0, lA, lB, acc0, acc1);
    const int lane = threadIdx.x & 63, w = threadIdx.x >> 6;
    const int wm = (w & 1) * 16, wn = (w >> 1) * 32;
    const int fr = lane & 15, orow = (lane >> 4) * 4;
    const int c0 = n0 + wn + fr, c1 = c0 + 16;
    const float b0 = bq[c0], b1 = bq[c1];
    #pragma unroll
    for (int r2 = 0; r2 < 4; ++r2) {
        int row = m0 + wm + orow + r2;
        Ea[(size_t)row*NN + c0] = exp2f((acc0[r2] + b0) * K2F);
        Ea[(size_t)row*NN + c1] = exp2f((acc1[r2] + b1) * K2F);
    }
}

// ---------------------------------------------------------------------------
// [4] scores, paired-rcp: Sp[nh][q][k] = sum_{n-pairs in slice nh}
//     (w0*B + w1*A) * rcp(A*B),  A=1+Ea[q,n0]*Ek[k,n0], B=1+Ea[q,n1]*Ek[k,n1]
// 64q x 64k tile, 4x4/thread, n sliced in 8 chunks of 128.
// ---------------------------------------------------------------------------
__global__ __launch_bounds__(256) void score_pair_kernel(
    const float* __restrict__ Ea,   // [512, 1024]
    const float* __restrict__ keys, // [2048, 1024] raw
    const float* __restrict__ watt, // [1024]
    float* __restrict__ Sp)         // [8][512][512]
{
    __shared__ float EaS[32][68];
    __shared__ float EkS[32][68];
    __shared__ float wS[32];
    const int tid = threadIdx.x;
    const int tx = tid & 15, ty = tid >> 4;
    const int kt = blockIdx.x;          // 0..7
    const int qt = blockIdx.y;          // 0..1
    const int bz = blockIdx.z;          // 0..31
    const int b = bz >> 3, nh = bz & 7;
    const int qrow0 = b*TQ + qt*64;
    const int krow0 = b*TK + kt*64;
    const int sr = tid >> 2;            // 0..63
    const int sc = (tid & 3) * 8;       // 0,8,16,24
    float acc[4][4] = {};
    const int nbeg = nh * 128;
    for (int nb = nbeg; nb < nbeg + 128; nb += 32) {
        float4 a0 = *(const float4*)(Ea + (size_t)(qrow0+sr)*NN + nb + sc);
        float4 a1 = *(const float4*)(Ea + (size_t)(qrow0+sr)*NN + nb + sc + 4);
        float4 k0 = *(const float4*)(keys + (size_t)(krow0+sr)*NN + nb + sc);
        float4 k1 = *(const float4*)(keys + (size_t)(krow0+sr)*NN + nb + sc + 4);
        k0.x = exp2f(k0.x*K2F); k0.y = exp2f(k0.y*K2F);
        k0.z = exp2f(k0.z*K2F); k0.w = exp2f(k0.w*K2F);
        k1.x = exp2f(k1.x*K2F); k1.y = exp2f(k1.y*K2F);
        k1.z = exp2f(k1.z*K2F); k1.w = exp2f(k1.w*K2F);
        EaS[sc+0][sr]=a0.x; EaS[sc+1][sr]=a0.y; EaS[sc+2][sr]=a0.z; EaS[sc+3][sr]=a0.w;
        EaS[sc+4][sr]=a1.x; EaS[sc+5][sr]=a1.y; EaS[sc+6][sr]=a1.z; EaS[sc+7][sr]=a1.w;
        EkS[sc+0][sr]=k0.x; EkS[sc+1][sr]=k0.y; EkS[sc+2][sr]=k0.z; EkS[sc+3][sr]=k0.w;
        EkS[sc+4][sr]=k1.x; EkS[sc+5][sr]=k1.y; EkS[sc+6][sr]=k1.z; EkS[sc+7][sr]=k1.w;
        if (tid < 32) wS[tid] = watt[nb + tid];
        __syncthreads();
        #pragma unroll
        for (int np = 0; np < 16; ++np) {
            float4 e0 = *(const float4*)&EaS[2*np  ][ty*4];
            float4 e1 = *(const float4*)&EaS[2*np+1][ty*4];
            float4 f0 = *(const float4*)&EkS[2*np  ][tx*4];
            float4 f1 = *(const float4*)&EkS[2*np+1][tx*4];
            float w0 = wS[2*np], w1 = wS[2*np+1];
            float ea0[4] = {e0.x,e0.y,e0.z,e0.w};
            float ea1[4] = {e1.x,e1.y,e1.z,e1.w};
            float ek0[4] = {f0.x,f0.y,f0.z,f0.w};
            float ek1[4] = {f1.x,f1.y,f1.z,f1.w};
            #pragma unroll
            for (int i = 0; i < 4; ++i) {
                #pragma unroll
                for (int j = 0; j < 4; ++j) {
                    float A  = fmaf(ea0[i], ek0[j], 1.0f);
                    float Bv = fmaf(ea1[i], ek1[j], 1.0f);
                    float num = fmaf(w0, Bv, w1 * A);
                    float den = A * Bv;
                    acc[i][j] = fmaf(num, __builtin_amdgcn_rcpf(den), acc[i][j]);
                }
            }
        }
        __syncthreads();
    }
    float* o = Sp + (size_t)nh * (512*512);
    #pragma unroll
    for (int i = 0; i < 4; ++i) {
        int row = qrow0 + ty*4 + i;
        #pragma unroll
        for (int j = 0; j < 4; ++j)
            o[(size_t)row*TK + kt*64 + tx*4 + j] = acc[i][j];
    }
}

// ---------------------------------------------------------------------------
// [5] softmax over k of (-2 * sum_h Sp[h]); writes P f32 (output 1) + Ph/Pl
// ---------------------------------------------------------------------------
__global__ __launch_bounds__(256) void softmax_kernel(
    const float* __restrict__ Sp, float* __restrict__ P,
    ushort* __restrict__ Ph, ushort* __restrict__ Pl)
{
    const int lane = threadIdx.x & 63;
    const int wid  = threadIdx.x >> 6;
    const int row  = blockIdx.x * 4 + wid;
    const size_t S = (size_t)512*512;
    float v[8];
    float m = -3.4e38f;
    #pragma unroll
    for (int j = 0; j < 8; ++j) {
        int k = lane + j*64;
        float s = 0.f;
        #pragma unroll
        for (int h = 0; h < 8; ++h)
            s += Sp[h*S + (size_t)row*TK + k];
        v[j] = -2.0f * s;
        m = fmaxf(m, v[j]);
    }
    #pragma unroll
    for (int off = 32; off; off >>= 1) m = fmaxf(m, __shfl_xor(m, off, 64));
    float sum = 0.f;
    #pragma unroll
    for (int j = 0; j < 8; ++j) { v[j] = exp2f((v[j] - m) * LOG2EF); sum += v[j]; }
    #pragma unroll
    for (int off = 32; off; off >>= 1) sum += __shfl_xor(sum, off, 64);
    float inv = 1.0f / sum;
    #pragma unroll
    for (int j = 0; j < 8; ++j) {
        int k = lane + j*64;
        float pv = v[j] * inv;
        P[(size_t)row * TK + k] = pv;
        ushort h, l; split2(pv, h, l);
        Ph[(size_t)row * TK + k] = h;
        Pl[(size_t)row * TK + k] = l;
    }
}

// ---------------------------------------------------------------------------
// [6] Cx = P @ V (per-batch), epilogue split2 -> Cxh/Cxl
// ---------------------------------------------------------------------------
__global__ __launch_bounds__(256) void mfma_pv_kernel(
    const ushort* __restrict__ Ph, const ushort* __restrict__ Pl,
    const ushort* __restrict__ Vth, const ushort* __restrict__ Vtl,
    ushort* __restrict__ Cxh, ushort* __restrict__ Cxl)
{
    __shared__ alignas(16) ushort lA[2*32*40];
    __shared__ alignas(16) ushort lB[2*64*40];
    const int m0 = blockIdx.y*32, n0 = blockIdx.x*64;
    const int batch = m0 >> 7;
    f32x4 acc0 = {0,0,0,0}, acc1 = {0,0,0,0};
    mfma_core(Ph, Pl, 512,
              Vth + (size_t)batch*(VS*TK), Vtl + (size_t)batch*(VS*TK), 512,
              512, m0, n0, lA, lB, acc0, acc1);
    const int lane = threadIdx.x & 63, w = threadIdx.x >> 6;
    const int wm = (w & 1) * 16, wn = (w >> 1) * 32;
    const int fr = lane & 15, orow = (lane >> 4) * 4;
    const int c0 = n0 + wn + fr, c1 = c0 + 16;
    #pragma unroll
    for (int r2 = 0; r2 < 4; ++r2) {
        int row = m0 + wm + orow + r2;
        ushort h, l;
        split2(acc0[r2], h, l);
        Cxh[(size_t)row*VS + c0] = h; Cxl[(size_t)row*VS + c0] = l;
        split2(acc1[r2], h, l);
        Cxh[(size_t)row*VS + c1] = h; Cxl[(size_t)row*VS + c1] = l;
    }
}

// ---------------------------------------------------------------------------
// [7] out = tanh([Q|Cx] @ Wout^T + bout), K=2048 via two mfma_core calls
// ---------------------------------------------------------------------------
__global__ __launch_bounds__(256) void mfma_out_kernel(
    const ushort* __restrict__ Qh, const ushort* __restrict__ Ql,
    const ushort* __restrict__ Cxh, const ushort* __restrict__ Cxl,
    const ushort* __restrict__ Woh, const ushort* __restrict__ Wol,
    const float* __restrict__ bout, float* __restrict__ out)
{
    __shared__ alignas(16) ushort lA[2*32*40];
    __shared__ alignas(16) ushort lB[2*64*40];
    const int m0 = blockIdx.y*32, n0 = blockIdx.x*64;
    f32x4 acc0 = {0,0,0,0}, acc1 = {0,0,0,0};
    mfma_core(Qh,  Ql,  1024, Woh,        Wol,        2048, 1024, m0, n0, lA, lB, acc0, acc1);
    mfma_core(Cxh, Cxl, 1024, Woh + 1024, Wol + 1024, 2048, 1024, m0, n0, lA, lB, acc0, acc1);
    const int lane = threadIdx.x & 63, w = threadIdx.x >> 6;
    const int wm = (w & 1) * 16, wn = (w >> 1) * 32;
    const int fr = lane & 15, orow = (lane >> 4) * 4;
    const int c0 = n0 + wn + fr, c1 = c0 + 16;
    const float b0 = bout[c0], b1 = bout[c1];
    #pragma unroll
    for (int r2 = 0; r2 < 4; ++r2) {
        int row = m0 + wm + orow + r2;
        out[(size_t)row*OS + c0] = tanhf(acc0[r2] + b0);
        out[(size_t)row*OS + c1] = tanhf(acc1[r2] + b1);
    }
}

// ---------------------------------------------------------------------------
extern "C" void kernel_launch(void* const* d_in, const int* in_sizes, int n_in,
                              void* d_out, int out_size, void* d_ws, size_t ws_size,
                              hipStream_t stream)
{
    const float* query  = (const float*)d_in[0];
    const float* keys   = (const float*)d_in[1];
    const float* values = (const float*)d_in[2];
    const float* Wq     = (const float*)d_in[3];
    const float* bq     = (const float*)d_in[4];
    const float* watt   = (const float*)d_in[5];
    // d_in[6] = b_att: dropped (softmax shift-invariance)
    const float* Wout   = (const float*)d_in[7];
    const float* bout   = (const float*)d_in[8];

    float* out = (float*)d_out;                    // output 0 (524288 f32)
    float* P   = out + (size_t)B_*TQ*OS;           // output 1 (262144 f32)

    // ws layout (32 MB):
    //  [ 0, 1M): Qh     [ 1, 2M): Ql
    //  [ 2, 6M): Woh    [ 6,10M): Wol
    //  [10,14M): Vth    [14,18M): Vtl
    //  [18,20M): Wqh -> dead after [3]; reused: Ph@18, Pl@18.5, Cxh@19
    //  [20,22M): Wql -> dead after [3]; reused: Cxl@20
    //  [22,24M): Ea
    //  [24,32M): Sp [8][512][512] f32
    char* base = (char*)d_ws;
    const size_t MB = 1u << 20;
    ushort* Qh  = (ushort*)(base + 0*MB);
    ushort* Ql  = (ushort*)(base + 1*MB);
    ushort* Woh = (ushort*)(base + 2*MB);
    ushort* Wol = (ushort*)(base + 6*MB);
    ushort* Vth = (ushort*)(base + 10*MB);
    ushort* Vtl = (ushort*)(base + 14*MB);
    ushort* Wqh = (ushort*)(base + 18*MB);
    ushort* Wql = (ushort*)(base + 20*MB);
    ushort* Ph  = (ushort*)(base + 18*MB);
    ushort* Pl  = (ushort*)(base + 18*MB + 512*1024);
    ushort* Cxh = (ushort*)(base + 19*MB);
    ushort* Cxl = (ushort*)(base + 20*MB);
    float*  Ea  = (float*) (base + 22*MB);
    float*  Sp  = (float*) (base + 24*MB);

    // [1] convert Q, Wq, Wout to hi/lo bf16
    cvt_fused_kernel<<<dim3(3584), dim3(256), 0, stream>>>(
        query, Wq, Wout, Qh, Ql, Wqh, Wql, Woh, Wol);
    // [2] V transpose + convert
    cvt_transpose_v_kernel<<<dim3(16, 8, 4), dim3(256), 0, stream>>>(values, Vth, Vtl);
    // [3] Ea = e^{2*(Q@Wq^T+bq)}
    mfma_a_exp_kernel<<<dim3(16, 16), dim3(256), 0, stream>>>(Qh, Ql, Wqh, Wql, bq, Ea);
    // [4] paired-rcp scores
    score_pair_kernel<<<dim3(8, 2, 32), dim3(256), 0, stream>>>(Ea, keys, watt, Sp);
    // [5] softmax -> P (output 1) + Ph/Pl
    softmax_kernel<<<dim3(128), dim3(256), 0, stream>>>(Sp, P, Ph, Pl);
    // [6] Cx = P@V -> hi/lo
    mfma_pv_kernel<<<dim3(16, 16), dim3(256), 0, stream>>>(Ph, Pl, Vth, Vtl, Cxh, Cxl);
    // [7] out = tanh([Q|Cx]@Wout^T + bout)
    mfma_out_kernel<<<dim3(16, 16), dim3(256), 0, stream>>>(
        Qh, Ql, Cxh, Cxl, Woh, Wol, bout, out);
}

// Round 5
// 108.423 us; speedup vs baseline: 1.0414x; 1.0414x over previous
//
#include <hip/hip_runtime.h>
#include <math.h>

static constexpr int B_  = 4;
static constexpr int TQ  = 128;
static constexpr int TK  = 512;
static constexpr int NN  = 1024;
static constexpr int QS  = 1024;
static constexpr int VS  = 1024;
static constexpr int OS  = 1024;

#define K2F    2.8853900817779268f   // 2*log2(e)
#define LOG2EF 1.4426950408889634f

typedef __attribute__((ext_vector_type(8))) short bf16x8;
typedef __attribute__((ext_vector_type(4))) float f32x4;

#define MFMA16(a,b,c) __builtin_amdgcn_mfma_f32_16x16x32_bf16((a),(b),(c),0,0,0)

// f32 -> bf16 round-to-nearest-even
__device__ __forceinline__ ushort bf16_rne(float x) {
    uint u = __float_as_uint(x);
    u += 0x7FFFu + ((u >> 16) & 1u);
    return (ushort)(u >> 16);
}
// split f32 into hi+lo bf16 (a ~= hi + lo, rel err ~2^-17)
__device__ __forceinline__ void split2(float x, ushort& h, ushort& l) {
    ushort hh = bf16_rne(x);
    float hv = __uint_as_float((uint)hh << 16);
    h = hh;
    l = bf16_rne(x - hv);
}

// ---------------------------------------------------------------------------
// [1] fused conversion: Q (512 blk), Wq (1024 blk), Wout (2048 blk) -> hi/lo
// ---------------------------------------------------------------------------
__global__ __launch_bounds__(256) void cvt_fused_kernel(
    const float* __restrict__ Q, const float* __restrict__ Wq,
    const float* __restrict__ Wo,
    ushort* __restrict__ Qh, ushort* __restrict__ Ql,
    ushort* __restrict__ Wqh, ushort* __restrict__ Wql,
    ushort* __restrict__ Woh, ushort* __restrict__ Wol)
{
    int bid = blockIdx.x;
    const float* src; ushort *h, *l; int idx;
    if (bid < 512)       { src = Q;  h = Qh;  l = Ql;  idx = bid*256 + threadIdx.x; }
    else if (bid < 1536) { src = Wq; h = Wqh; l = Wql; idx = (bid-512)*256 + threadIdx.x; }
    else                 { src = Wo; h = Woh; l = Wol; idx = (bid-1536)*256 + threadIdx.x; }
    float4 v = ((const float4*)src)[idx];
    ushort4 hh, ll;
    split2(v.x, hh.x, ll.x); split2(v.y, hh.y, ll.y);
    split2(v.z, hh.z, ll.z); split2(v.w, hh.w, ll.w);
    ((ushort4*)h)[idx] = hh;
    ((ushort4*)l)[idx] = ll;
}

// ---------------------------------------------------------------------------
// [2] V [b][k=512][v=1024] -> Vt hi/lo [b][v=1024][k=512]
// ---------------------------------------------------------------------------
__global__ __launch_bounds__(256) void cvt_transpose_v_kernel(
    const float* __restrict__ V, ushort* __restrict__ Th, ushort* __restrict__ Tl)
{
    __shared__ float tile[64][65];
    const int b = blockIdx.z, k0 = blockIdx.y * 64, v0 = blockIdx.x * 64;
    const int t = threadIdx.x;
    const float* src = V + ((size_t)b*TK + k0)*VS + v0;
    #pragma unroll
    for (int p = 0; p < 4; ++p) {
        int r = (t >> 4) + p*16, c = (t & 15) * 4;
        float4 vv = *(const float4*)(src + (size_t)r*VS + c);
        tile[r][c] = vv.x; tile[r][c+1] = vv.y; tile[r][c+2] = vv.z; tile[r][c+3] = vv.w;
    }
    __syncthreads();
    ushort* dh = Th + (size_t)b*(VS*TK) + (size_t)v0*TK + k0;
    ushort* dl = Tl + (size_t)b*(VS*TK) + (size_t)v0*TK + k0;
    #pragma unroll
    for (int p = 0; p < 4; ++p) {
        int vr = (t >> 4) + p*16, kc = (t & 15) * 4;
        ushort4 hh, ll;
        split2(tile[kc+0][vr], hh.x, ll.x);
        split2(tile[kc+1][vr], hh.y, ll.y);
        split2(tile[kc+2][vr], hh.z, ll.z);
        split2(tile[kc+3][vr], hh.w, ll.w);
        *(ushort4*)(dh + (size_t)vr*TK + kc) = hh;
        *(ushort4*)(dl + (size_t)vr*TK + kc) = ll;
    }
}

// ---------------------------------------------------------------------------
// [3/7] split-bf16 NT MFMA GEMM, M=512; 64x64 tile, 4 waves x 32x32,
// K-split via blockIdx.z (round-3 proven structure).
// ---------------------------------------------------------------------------
__global__ __launch_bounds__(256) void mfma_nt_kernel(
    const ushort* __restrict__ Ah, const ushort* __restrict__ Al,
    const ushort* __restrict__ Bh, const ushort* __restrict__ Bl,
    float* __restrict__ Cp, int lda, int ldb, int Nout, int kchunk, int bstride)
{
    __shared__ alignas(16) ushort lA[2][64][40];
    __shared__ alignas(16) ushort lB[2][64][40];
    const int t = threadIdx.x;
    const int m0 = blockIdx.y * 64, n0 = blockIdx.x * 64, kz = blockIdx.z;
    const int k0 = kz * kchunk;
    const int batch = m0 >> 7;
    const ushort* bhp = Bh + (size_t)batch * bstride;
    const ushort* blp = Bl + (size_t)batch * bstride;
    const int srow = t >> 2, skc = (t & 3) * 8;
    const int lane = t & 63, w = t >> 6;
    const int wm = (w >> 1) * 32, wn = (w & 1) * 32;
    const int fr = lane & 15, fg = (lane >> 4) * 8;

    f32x4 acc00 = {0,0,0,0}, acc01 = {0,0,0,0}, acc10 = {0,0,0,0}, acc11 = {0,0,0,0};

    for (int kb = k0; kb < k0 + kchunk; kb += 32) {
        uint4 va_h = *(const uint4*)(Ah  + (size_t)(m0+srow)*lda + kb + skc);
        uint4 va_l = *(const uint4*)(Al  + (size_t)(m0+srow)*lda + kb + skc);
        uint4 vb_h = *(const uint4*)(bhp + (size_t)(n0+srow)*ldb + kb + skc);
        uint4 vb_l = *(const uint4*)(blp + (size_t)(n0+srow)*ldb + kb + skc);
        *(uint4*)&lA[0][srow][skc] = va_h;
        *(uint4*)&lA[1][srow][skc] = va_l;
        *(uint4*)&lB[0][srow][skc] = vb_h;
        *(uint4*)&lB[1][srow][skc] = vb_l;
        __syncthreads();
        bf16x8 ah0 = *(const bf16x8*)&lA[0][wm + fr     ][fg];
        bf16x8 ah1 = *(const bf16x8*)&lA[0][wm + 16 + fr][fg];
        bf16x8 al0 = *(const bf16x8*)&lA[1][wm + fr     ][fg];
        bf16x8 al1 = *(const bf16x8*)&lA[1][wm + 16 + fr][fg];
        bf16x8 bh0 = *(const bf16x8*)&lB[0][wn + fr     ][fg];
        bf16x8 bh1 = *(const bf16x8*)&lB[0][wn + 16 + fr][fg];
        bf16x8 bl0 = *(const bf16x8*)&lB[1][wn + fr     ][fg];
        bf16x8 bl1 = *(const bf16x8*)&lB[1][wn + 16 + fr][fg];
        acc00 = MFMA16(ah0, bh0, acc00);
        acc00 = MFMA16(al0, bh0, acc00);
        acc00 = MFMA16(ah0, bl0, acc00);
        acc01 = MFMA16(ah0, bh1, acc01);
        acc01 = MFMA16(al0, bh1, acc01);
        acc01 = MFMA16(ah0, bl1, acc01);
        acc10 = MFMA16(ah1, bh0, acc10);
        acc10 = MFMA16(al1, bh0, acc10);
        acc10 = MFMA16(ah1, bl0, acc10);
        acc11 = MFMA16(ah1, bh1, acc11);
        acc11 = MFMA16(al1, bh1, acc11);
        acc11 = MFMA16(ah1, bl1, acc11);
        __syncthreads();
    }
    float* o = Cp + (size_t)kz * 512 * Nout;
    const int orow = (lane >> 4) * 4;
    #pragma unroll
    for (int r2 = 0; r2 < 4; ++r2) {
        o[(size_t)(m0+wm+orow+r2)*Nout      + n0+wn+fr]      = acc00[r2];
        o[(size_t)(m0+wm+orow+r2)*Nout      + n0+wn+16+fr]   = acc01[r2];
        o[(size_t)(m0+wm+16+orow+r2)*Nout   + n0+wn+fr]      = acc10[r2];
        o[(size_t)(m0+wm+16+orow+r2)*Nout   + n0+wn+16+fr]   = acc11[r2];
    }
}

// ---------------------------------------------------------------------------
// [9] out-GEMM MFMA: A = [Q | Cx] by kz (K=2048 split 4), B = Wout hi/lo
// ---------------------------------------------------------------------------
__global__ __launch_bounds__(256) void mfma_out_kernel(
    const ushort* __restrict__ Qh, const ushort* __restrict__ Ql,
    const ushort* __restrict__ Cxh, const ushort* __restrict__ Cxl,
    const ushort* __restrict__ Wh, const ushort* __restrict__ Wl,
    float* __restrict__ Fp)
{
    __shared__ alignas(16) ushort lA[2][64][40];
    __shared__ alignas(16) ushort lB[2][64][40];
    const int t = threadIdx.x;
    const int m0 = blockIdx.y * 64, n0 = blockIdx.x * 64, kz = blockIdx.z;
    const ushort* ah_p = (kz < 2) ? Qh : Cxh;
    const ushort* al_p = (kz < 2) ? Ql : Cxl;
    const int akoff = (kz & 1) * 512;
    const int bkoff = kz * 512;
    const int srow = t >> 2, skc = (t & 3) * 8;
    const int lane = t & 63, w = t >> 6;
    const int wm = (w >> 1) * 32, wn = (w & 1) * 32;
    const int fr = lane & 15, fg = (lane >> 4) * 8;

    f32x4 acc00 = {0,0,0,0}, acc01 = {0,0,0,0}, acc10 = {0,0,0,0}, acc11 = {0,0,0,0};

    for (int kk = 0; kk < 512; kk += 32) {
        uint4 va_h = *(const uint4*)(ah_p + (size_t)(m0+srow)*1024 + akoff + kk + skc);
        uint4 va_l = *(const uint4*)(al_p + (size_t)(m0+srow)*1024 + akoff + kk + skc);
        uint4 vb_h = *(const uint4*)(Wh   + (size_t)(n0+srow)*2048 + bkoff + kk + skc);
        uint4 vb_l = *(const uint4*)(Wl   + (size_t)(n0+srow)*2048 + bkoff + kk + skc);
        *(uint4*)&lA[0][srow][skc] = va_h;
        *(uint4*)&lA[1][srow][skc] = va_l;
        *(uint4*)&lB[0][srow][skc] = vb_h;
        *(uint4*)&lB[1][srow][skc] = vb_l;
        __syncthreads();
        bf16x8 ah0 = *(const bf16x8*)&lA[0][wm + fr     ][fg];
        bf16x8 ah1 = *(const bf16x8*)&lA[0][wm + 16 + fr][fg];
        bf16x8 al0 = *(const bf16x8*)&lA[1][wm + fr     ][fg];
        bf16x8 al1 = *(const bf16x8*)&lA[1][wm + 16 + fr][fg];
        bf16x8 bh0 = *(const bf16x8*)&lB[0][wn + fr     ][fg];
        bf16x8 bh1 = *(const bf16x8*)&lB[0][wn + 16 + fr][fg];
        bf16x8 bl0 = *(const bf16x8*)&lB[1][wn + fr     ][fg];
        bf16x8 bl1 = *(const bf16x8*)&lB[1][wn + 16 + fr][fg];
        acc00 = MFMA16(ah0, bh0, acc00);
        acc00 = MFMA16(al0, bh0, acc00);
        acc00 = MFMA16(ah0, bl0, acc00);
        acc01 = MFMA16(ah0, bh1, acc01);
        acc01 = MFMA16(al0, bh1, acc01);
        acc01 = MFMA16(ah0, bl1, acc01);
        acc10 = MFMA16(ah1, bh0, acc10);
        acc10 = MFMA16(al1, bh0, acc10);
        acc10 = MFMA16(ah1, bl0, acc10);
        acc11 = MFMA16(ah1, bh1, acc11);
        acc11 = MFMA16(al1, bh1, acc11);
        acc11 = MFMA16(ah1, bl1, acc11);
        __syncthreads();
    }
    float* o = Fp + (size_t)kz * 512 * 1024;
    const int orow = (lane >> 4) * 4;
    #pragma unroll
    for (int r2 = 0; r2 < 4; ++r2) {
        o[(size_t)(m0+wm+orow+r2)*1024    + n0+wn+fr]    = acc00[r2];
        o[(size_t)(m0+wm+orow+r2)*1024    + n0+wn+16+fr] = acc01[r2];
        o[(size_t)(m0+wm+16+orow+r2)*1024 + n0+wn+fr]    = acc10[r2];
        o[(size_t)(m0+wm+16+orow+r2)*1024 + n0+wn+16+fr] = acc11[r2];
    }
}

// ---------------------------------------------------------------------------
// [4] Ea = exp2((p0+p1+bq)*2log2e)
// ---------------------------------------------------------------------------
__global__ __launch_bounds__(256) void exp_combine_kernel(
    const float* __restrict__ Ap, const float* __restrict__ bias,
    float* __restrict__ E)
{
    int i = blockIdx.x * 256 + threadIdx.x;
    float4 p0 = ((const float4*)Ap)[i];
    float4 p1 = ((const float4*)(Ap + (size_t)B_*TQ*NN))[i];
    float4 bb = ((const float4*)bias)[i & 255];
    float4 r;
    r.x = exp2f((p0.x + p1.x + bb.x) * K2F);
    r.y = exp2f((p0.y + p1.y + bb.y) * K2F);
    r.z = exp2f((p0.z + p1.z + bb.z) * K2F);
    r.w = exp2f((p0.w + p1.w + bb.w) * K2F);
    ((float4*)E)[i] = r;
}

// ---------------------------------------------------------------------------
// [5] scores, scalar-operand form. Lane = k (64/block-tile); wave id forced
// into SGPR so Ea/watt loads are s_load (scalar pipe); keys chunk lives in
// 64 VGPRs per lane. No LDS, no barriers. 2 fma + 1 rcp per eval.
// Sp[nh][q][k] = sum_{n in chunk nh} w[n] * rcp(1 + Ea[q,n]*e^{2*keys[k,n]})
// ---------------------------------------------------------------------------
__global__ __launch_bounds__(512, 4) void score_sreg_kernel(
    const float* __restrict__ Ea,   // [512, 1024]
    const float* __restrict__ keys, // [2048, 1024]
    const float* __restrict__ watt, // [1024]
    float* __restrict__ Sp)         // [16][512][512]
{
    const int lane = threadIdx.x & 63;
    const int wid  = __builtin_amdgcn_readfirstlane(threadIdx.x >> 6);  // 0..7, SGPR
    const int kt = blockIdx.x;      // 0..7
    const int b  = blockIdx.y;      // 0..3
    const int nh = blockIdx.z;      // 0..15
    const int nbeg = nh * 64;
    const int krow = b*TK + kt*64 + lane;

    // per-lane: load + exp2 its keys chunk (64 values -> 64 VGPRs)
    float ek[64];
    const float* kp = keys + (size_t)krow*NN + nbeg;
    #pragma unroll
    for (int n4 = 0; n4 < 16; ++n4) {
        float4 kv = *(const float4*)(kp + n4*4);
        ek[n4*4+0] = exp2f(kv.x * K2F);
        ek[n4*4+1] = exp2f(kv.y * K2F);
        ek[n4*4+2] = exp2f(kv.z * K2F);
        ek[n4*4+3] = exp2f(kv.w * K2F);
    }
    const float* __restrict__ wp = watt + nbeg;                  // uniform
    const float* __restrict__ eaq = Ea + (size_t)(b*TQ + wid*16)*NN + nbeg;  // uniform
    float* op = Sp + ((size_t)nh*512 + (size_t)(b*TQ + wid*16))*TK + kt*64 + lane;

    for (int qi = 0; qi < 16; ++qi) {
        float s0 = 0.f, s1 = 0.f, s2 = 0.f, s3 = 0.f;
        #pragma unroll
        for (int n = 0; n < 64; n += 4) {
            float A0 = fmaf(eaq[n+0], ek[n+0], 1.0f);
            float A1 = fmaf(eaq[n+1], ek[n+1], 1.0f);
            float A2 = fmaf(eaq[n+2], ek[n+2], 1.0f);
            float A3 = fmaf(eaq[n+3], ek[n+3], 1.0f);
            s0 = fmaf(wp[n+0], __builtin_amdgcn_rcpf(A0), s0);
            s1 = fmaf(wp[n+1], __builtin_amdgcn_rcpf(A1), s1);
            s2 = fmaf(wp[n+2], __builtin_amdgcn_rcpf(A2), s2);
            s3 = fmaf(wp[n+3], __builtin_amdgcn_rcpf(A3), s3);
        }
        *op = (s0 + s1) + (s2 + s3);
        eaq += NN;
        op += TK;
    }
}

// ---------------------------------------------------------------------------
// [6] softmax over k of (-2 * sum_{h<16} Sp[h]); writes P f32 + Ph/Pl
// ---------------------------------------------------------------------------
__global__ __launch_bounds__(256) void softmax_kernel(
    const float* __restrict__ Sp, float* __restrict__ P,
    ushort* __restrict__ Ph, ushort* __restrict__ Pl)
{
    const int lane = threadIdx.x & 63;
    const int wid  = threadIdx.x >> 6;
    const int row  = blockIdx.x * 4 + wid;
    const size_t S = (size_t)512*512;
    float v[8];
    float m = -3.4e38f;
    #pragma unroll
    for (int j = 0; j < 8; ++j) {
        int k = lane + j*64;
        float s = 0.f;
        #pragma unroll
        for (int h = 0; h < 16; ++h)
            s += Sp[h*S + (size_t)row*TK + k];
        v[j] = -2.0f * s;
        m = fmaxf(m, v[j]);
    }
    #pragma unroll
    for (int off = 32; off; off >>= 1) m = fmaxf(m, __shfl_xor(m, off, 64));
    float sum = 0.f;
    #pragma unroll
    for (int j = 0; j < 8; ++j) { v[j] = exp2f((v[j] - m) * LOG2EF); sum += v[j]; }
    #pragma unroll
    for (int off = 32; off; off >>= 1) sum += __shfl_xor(sum, off, 64);
    float inv = 1.0f / sum;
    #pragma unroll
    for (int j = 0; j < 8; ++j) {
        int k = lane + j*64;
        float pv = v[j] * inv;
        P[(size_t)row * TK + k] = pv;
        ushort h, l; split2(pv, h, l);
        Ph[(size_t)row * TK + k] = h;
        Pl[(size_t)row * TK + k] = l;
    }
}

// ---------------------------------------------------------------------------
// [8] Cx = Ep0+Ep1 -> hi/lo bf16
// ---------------------------------------------------------------------------
__global__ __launch_bounds__(256) void combine_cvt_kernel(
    const float* __restrict__ Ep, ushort* __restrict__ Ch, ushort* __restrict__ Cl)
{
    int i = blockIdx.x * 256 + threadIdx.x;
    float4 p0 = ((const float4*)Ep)[i];
    float4 p1 = ((const float4*)(Ep + (size_t)B_*TQ*VS))[i];
    float4 s = {p0.x+p1.x, p0.y+p1.y, p0.z+p1.z, p0.w+p1.w};
    ushort4 hh, ll;
    split2(s.x, hh.x, ll.x); split2(s.y, hh.y, ll.y);
    split2(s.z, hh.z, ll.z); split2(s.w, hh.w, ll.w);
    ((ushort4*)Ch)[i] = hh;
    ((ushort4*)Cl)[i] = ll;
}

// ---------------------------------------------------------------------------
// [10] out = tanh(sum Fp + bias)
// ---------------------------------------------------------------------------
__global__ __launch_bounds__(256) void tanh_combine_kernel(
    const float* __restrict__ Fp, const float* __restrict__ bias,
    float* __restrict__ out)
{
    int i = blockIdx.x * 256 + threadIdx.x;
    const size_t S = (size_t)B_*TQ*OS;
    float4 p0 = ((const float4*)Fp)[i];
    float4 p1 = ((const float4*)(Fp + S))[i];
    float4 p2 = ((const float4*)(Fp + 2*S))[i];
    float4 p3 = ((const float4*)(Fp + 3*S))[i];
    float4 bb = ((const float4*)bias)[i & 255];
    float4 r;
    r.x = tanhf(p0.x + p1.x + p2.x + p3.x + bb.x);
    r.y = tanhf(p0.y + p1.y + p2.y + p3.y + bb.y);
    r.z = tanhf(p0.z + p1.z + p2.z + p3.z + bb.z);
    r.w = tanhf(p0.w + p1.w + p2.w + p3.w + bb.w);
    ((float4*)out)[i] = r;
}

// ---------------------------------------------------------------------------
extern "C" void kernel_launch(void* const* d_in, const int* in_sizes, int n_in,
                              void* d_out, int out_size, void* d_ws, size_t ws_size,
                              hipStream_t stream)
{
    const float* query  = (const float*)d_in[0];
    const float* keys   = (const float*)d_in[1];
    const float* values = (const float*)d_in[2];
    const float* Wq     = (const float*)d_in[3];
    const float* bq     = (const float*)d_in[4];
    const float* watt   = (const float*)d_in[5];
    // d_in[6] = b_att: dropped (softmax shift-invariance)
    const float* Wout   = (const float*)d_in[7];
    const float* bout   = (const float*)d_in[8];

    float* out = (float*)d_out;                    // output 0 (524288 f32)
    float* P   = out + (size_t)B_*TQ*OS;           // output 1 (262144 f32)

    // ws (256 MiB available; fill kernels showed WRITE_SIZE=256MiB) — fully
    // disjoint layout, 59 MB used, no aliasing.
    char* base = (char*)d_ws;
    const size_t MB = 1u << 20;
    ushort* Qh  = (ushort*)(base +  0*MB);
    ushort* Ql  = (ushort*)(base +  1*MB);
    ushort* Wqh = (ushort*)(base +  2*MB);
    ushort* Wql = (ushort*)(base +  4*MB);
    ushort* Woh = (ushort*)(base +  6*MB);
    ushort* Wol = (ushort*)(base + 10*MB);
    ushort* Vth = (ushort*)(base + 14*MB);
    ushort* Vtl = (ushort*)(base + 18*MB);
    float*  Ap  = (float*) (base + 22*MB);   // [2][512][1024]
    float*  Ea  = (float*) (base + 26*MB);   // [512][1024]
    float*  Sp  = (float*) (base + 28*MB);   // [16][512][512] = 16 MB
    ushort* Ph  = (ushort*)(base + 44*MB);
    ushort* Pl  = (ushort*)(base + 44*MB + 512*1024);
    float*  Ep  = (float*) (base + 45*MB);   // [2][512][1024]
    ushort* Cxh = (ushort*)(base + 49*MB);
    ushort* Cxl = (ushort*)(base + 50*MB);
    float*  Fp  = (float*) (base + 51*MB);   // [4][512][1024]

    // [1] convert Q, Wq, Wout to hi/lo bf16
    cvt_fused_kernel<<<dim3(3584), dim3(256), 0, stream>>>(
        query, Wq, Wout, Qh, Ql, Wqh, Wql, Woh, Wol);
    // [2] V transpose + convert
    cvt_transpose_v_kernel<<<dim3(16, 8, 4), dim3(256), 0, stream>>>(values, Vth, Vtl);
    // [3] A-GEMM partials: Q @ Wq^T  (K=1024 split 2)
    mfma_nt_kernel<<<dim3(16, 8, 2), dim3(256), 0, stream>>>(
        Qh, Ql, Wqh, Wql, Ap, 1024, 1024, 1024, 512, 0);
    // [4] Ea = e^{2*(Aq+bq)}
    exp_combine_kernel<<<dim3(512), dim3(256), 0, stream>>>(Ap, bq, Ea);
    // [5] scores (scalar-operand, 16 n-slices)
    score_sreg_kernel<<<dim3(8, 4, 16), dim3(512), 0, stream>>>(Ea, keys, watt, Sp);
    // [6] softmax -> P (output 1) + Ph/Pl
    softmax_kernel<<<dim3(128), dim3(256), 0, stream>>>(Sp, P, Ph, Pl);
    // [7] PV partials: P @ V (per-batch, K=512 split 2)
    mfma_nt_kernel<<<dim3(16, 8, 2), dim3(256), 0, stream>>>(
        Ph, Pl, Vth, Vtl, Ep, 512, 512, 1024, 256, VS*TK);
    // [8] Cx hi/lo
    combine_cvt_kernel<<<dim3(512), dim3(256), 0, stream>>>(Ep, Cxh, Cxl);
    // [9] out-GEMM partials (K=2048 split 4)
    mfma_out_kernel<<<dim3(16, 8, 4), dim3(256), 0, stream>>>(
        Qh, Ql, Cxh, Cxl, Woh, Wol, Fp);
    // [10] out = tanh(sum + bout)
    tanh_combine_kernel<<<dim3(512), dim3(256), 0, stream>>>(Fp, bout, out);
}

// Round 6
// 107.217 us; speedup vs baseline: 1.0531x; 1.0113x over previous
//
#include <hip/hip_runtime.h>
#include <math.h>

static constexpr int B_  = 4;
static constexpr int TQ  = 128;
static constexpr int TK  = 512;
static constexpr int NN  = 1024;
static constexpr int QS  = 1024;
static constexpr int VS  = 1024;
static constexpr int OS  = 1024;

#define K2F    2.8853900817779268f   // 2*log2(e)
#define LOG2EF 1.4426950408889634f

typedef __attribute__((ext_vector_type(8))) short bf16x8;
typedef __attribute__((ext_vector_type(4))) float f32x4;

#define MFMA16(a,b,c) __builtin_amdgcn_mfma_f32_16x16x32_bf16((a),(b),(c),0,0,0)

// f32 -> bf16 round-to-nearest-even
__device__ __forceinline__ ushort bf16_rne(float x) {
    uint u = __float_as_uint(x);
    u += 0x7FFFu + ((u >> 16) & 1u);
    return (ushort)(u >> 16);
}
// split f32 into hi+lo bf16 (a ~= hi + lo, rel err ~2^-17)
__device__ __forceinline__ void split2(float x, ushort& h, ushort& l) {
    ushort hh = bf16_rne(x);
    float hv = __uint_as_float((uint)hh << 16);
    h = hh;
    l = bf16_rne(x - hv);
}

// ---------------------------------------------------------------------------
// [1] fused conversion: Q (512 blk), Wq (1024 blk), Wout (2048 blk) -> hi/lo
// ---------------------------------------------------------------------------
__global__ __launch_bounds__(256) void cvt_fused_kernel(
    const float* __restrict__ Q, const float* __restrict__ Wq,
    const float* __restrict__ Wo,
    ushort* __restrict__ Qh, ushort* __restrict__ Ql,
    ushort* __restrict__ Wqh, ushort* __restrict__ Wql,
    ushort* __restrict__ Woh, ushort* __restrict__ Wol)
{
    int bid = blockIdx.x;
    const float* src; ushort *h, *l; int idx;
    if (bid < 512)       { src = Q;  h = Qh;  l = Ql;  idx = bid*256 + threadIdx.x; }
    else if (bid < 1536) { src = Wq; h = Wqh; l = Wql; idx = (bid-512)*256 + threadIdx.x; }
    else                 { src = Wo; h = Woh; l = Wol; idx = (bid-1536)*256 + threadIdx.x; }
    float4 v = ((const float4*)src)[idx];
    ushort4 hh, ll;
    split2(v.x, hh.x, ll.x); split2(v.y, hh.y, ll.y);
    split2(v.z, hh.z, ll.z); split2(v.w, hh.w, ll.w);
    ((ushort4*)h)[idx] = hh;
    ((ushort4*)l)[idx] = ll;
}

// ---------------------------------------------------------------------------
// [2] V [b][k=512][v=1024] -> Vt hi/lo [b][v=1024][k=512]
// ---------------------------------------------------------------------------
__global__ __launch_bounds__(256) void cvt_transpose_v_kernel(
    const float* __restrict__ V, ushort* __restrict__ Th, ushort* __restrict__ Tl)
{
    __shared__ float tile[64][65];
    const int b = blockIdx.z, k0 = blockIdx.y * 64, v0 = blockIdx.x * 64;
    const int t = threadIdx.x;
    const float* src = V + ((size_t)b*TK + k0)*VS + v0;
    #pragma unroll
    for (int p = 0; p < 4; ++p) {
        int r = (t >> 4) + p*16, c = (t & 15) * 4;
        float4 vv = *(const float4*)(src + (size_t)r*VS + c);
        tile[r][c] = vv.x; tile[r][c+1] = vv.y; tile[r][c+2] = vv.z; tile[r][c+3] = vv.w;
    }
    __syncthreads();
    ushort* dh = Th + (size_t)b*(VS*TK) + (size_t)v0*TK + k0;
    ushort* dl = Tl + (size_t)b*(VS*TK) + (size_t)v0*TK + k0;
    #pragma unroll
    for (int p = 0; p < 4; ++p) {
        int vr = (t >> 4) + p*16, kc = (t & 15) * 4;
        ushort4 hh, ll;
        split2(tile[kc+0][vr], hh.x, ll.x);
        split2(tile[kc+1][vr], hh.y, ll.y);
        split2(tile[kc+2][vr], hh.z, ll.z);
        split2(tile[kc+3][vr], hh.w, ll.w);
        *(ushort4*)(dh + (size_t)vr*TK + kc) = hh;
        *(ushort4*)(dl + (size_t)vr*TK + kc) = ll;
    }
}

// ---------------------------------------------------------------------------
// [3/7] split-bf16 NT MFMA GEMM, M=512; 64x64 tile, 4 waves x 32x32,
// K-split via blockIdx.z (round-3 proven structure).
// ---------------------------------------------------------------------------
__global__ __launch_bounds__(256) void mfma_nt_kernel(
    const ushort* __restrict__ Ah, const ushort* __restrict__ Al,
    const ushort* __restrict__ Bh, const ushort* __restrict__ Bl,
    float* __restrict__ Cp, int lda, int ldb, int Nout, int kchunk, int bstride)
{
    __shared__ alignas(16) ushort lA[2][64][40];
    __shared__ alignas(16) ushort lB[2][64][40];
    const int t = threadIdx.x;
    const int m0 = blockIdx.y * 64, n0 = blockIdx.x * 64, kz = blockIdx.z;
    const int k0 = kz * kchunk;
    const int batch = m0 >> 7;
    const ushort* bhp = Bh + (size_t)batch * bstride;
    const ushort* blp = Bl + (size_t)batch * bstride;
    const int srow = t >> 2, skc = (t & 3) * 8;
    const int lane = t & 63, w = t >> 6;
    const int wm = (w >> 1) * 32, wn = (w & 1) * 32;
    const int fr = lane & 15, fg = (lane >> 4) * 8;

    f32x4 acc00 = {0,0,0,0}, acc01 = {0,0,0,0}, acc10 = {0,0,0,0}, acc11 = {0,0,0,0};

    for (int kb = k0; kb < k0 + kchunk; kb += 32) {
        uint4 va_h = *(const uint4*)(Ah  + (size_t)(m0+srow)*lda + kb + skc);
        uint4 va_l = *(const uint4*)(Al  + (size_t)(m0+srow)*lda + kb + skc);
        uint4 vb_h = *(const uint4*)(bhp + (size_t)(n0+srow)*ldb + kb + skc);
        uint4 vb_l = *(const uint4*)(blp + (size_t)(n0+srow)*ldb + kb + skc);
        *(uint4*)&lA[0][srow][skc] = va_h;
        *(uint4*)&lA[1][srow][skc] = va_l;
        *(uint4*)&lB[0][srow][skc] = vb_h;
        *(uint4*)&lB[1][srow][skc] = vb_l;
        __syncthreads();
        bf16x8 ah0 = *(const bf16x8*)&lA[0][wm + fr     ][fg];
        bf16x8 ah1 = *(const bf16x8*)&lA[0][wm + 16 + fr][fg];
        bf16x8 al0 = *(const bf16x8*)&lA[1][wm + fr     ][fg];
        bf16x8 al1 = *(const bf16x8*)&lA[1][wm + 16 + fr][fg];
        bf16x8 bh0 = *(const bf16x8*)&lB[0][wn + fr     ][fg];
        bf16x8 bh1 = *(const bf16x8*)&lB[0][wn + 16 + fr][fg];
        bf16x8 bl0 = *(const bf16x8*)&lB[1][wn + fr     ][fg];
        bf16x8 bl1 = *(const bf16x8*)&lB[1][wn + 16 + fr][fg];
        acc00 = MFMA16(ah0, bh0, acc00);
        acc00 = MFMA16(al0, bh0, acc00);
        acc00 = MFMA16(ah0, bl0, acc00);
        acc01 = MFMA16(ah0, bh1, acc01);
        acc01 = MFMA16(al0, bh1, acc01);
        acc01 = MFMA16(ah0, bl1, acc01);
        acc10 = MFMA16(ah1, bh0, acc10);
        acc10 = MFMA16(al1, bh0, acc10);
        acc10 = MFMA16(ah1, bl0, acc10);
        acc11 = MFMA16(ah1, bh1, acc11);
        acc11 = MFMA16(al1, bh1, acc11);
        acc11 = MFMA16(ah1, bl1, acc11);
        __syncthreads();
    }
    float* o = Cp + (size_t)kz * 512 * Nout;
    const int orow = (lane >> 4) * 4;
    #pragma unroll
    for (int r2 = 0; r2 < 4; ++r2) {
        o[(size_t)(m0+wm+orow+r2)*Nout      + n0+wn+fr]      = acc00[r2];
        o[(size_t)(m0+wm+orow+r2)*Nout      + n0+wn+16+fr]   = acc01[r2];
        o[(size_t)(m0+wm+16+orow+r2)*Nout   + n0+wn+fr]      = acc10[r2];
        o[(size_t)(m0+wm+16+orow+r2)*Nout   + n0+wn+16+fr]   = acc11[r2];
    }
}

// ---------------------------------------------------------------------------
// [9] out-GEMM MFMA: A = [Q | Cx] by kz (K=2048 split 4), B = Wout hi/lo
// ---------------------------------------------------------------------------
__global__ __launch_bounds__(256) void mfma_out_kernel(
    const ushort* __restrict__ Qh, const ushort* __restrict__ Ql,
    const ushort* __restrict__ Cxh, const ushort* __restrict__ Cxl,
    const ushort* __restrict__ Wh, const ushort* __restrict__ Wl,
    float* __restrict__ Fp)
{
    __shared__ alignas(16) ushort lA[2][64][40];
    __shared__ alignas(16) ushort lB[2][64][40];
    const int t = threadIdx.x;
    const int m0 = blockIdx.y * 64, n0 = blockIdx.x * 64, kz = blockIdx.z;
    const ushort* ah_p = (kz < 2) ? Qh : Cxh;
    const ushort* al_p = (kz < 2) ? Ql : Cxl;
    const int akoff = (kz & 1) * 512;
    const int bkoff = kz * 512;
    const int srow = t >> 2, skc = (t & 3) * 8;
    const int lane = t & 63, w = t >> 6;
    const int wm = (w >> 1) * 32, wn = (w & 1) * 32;
    const int fr = lane & 15, fg = (lane >> 4) * 8;

    f32x4 acc00 = {0,0,0,0}, acc01 = {0,0,0,0}, acc10 = {0,0,0,0}, acc11 = {0,0,0,0};

    for (int kk = 0; kk < 512; kk += 32) {
        uint4 va_h = *(const uint4*)(ah_p + (size_t)(m0+srow)*1024 + akoff + kk + skc);
        uint4 va_l = *(const uint4*)(al_p + (size_t)(m0+srow)*1024 + akoff + kk + skc);
        uint4 vb_h = *(const uint4*)(Wh   + (size_t)(n0+srow)*2048 + bkoff + kk + skc);
        uint4 vb_l = *(const uint4*)(Wl   + (size_t)(n0+srow)*2048 + bkoff + kk + skc);
        *(uint4*)&lA[0][srow][skc] = va_h;
        *(uint4*)&lA[1][srow][skc] = va_l;
        *(uint4*)&lB[0][srow][skc] = vb_h;
        *(uint4*)&lB[1][srow][skc] = vb_l;
        __syncthreads();
        bf16x8 ah0 = *(const bf16x8*)&lA[0][wm + fr     ][fg];
        bf16x8 ah1 = *(const bf16x8*)&lA[0][wm + 16 + fr][fg];
        bf16x8 al0 = *(const bf16x8*)&lA[1][wm + fr     ][fg];
        bf16x8 al1 = *(const bf16x8*)&lA[1][wm + 16 + fr][fg];
        bf16x8 bh0 = *(const bf16x8*)&lB[0][wn + fr     ][fg];
        bf16x8 bh1 = *(const bf16x8*)&lB[0][wn + 16 + fr][fg];
        bf16x8 bl0 = *(const bf16x8*)&lB[1][wn + fr     ][fg];
        bf16x8 bl1 = *(const bf16x8*)&lB[1][wn + 16 + fr][fg];
        acc00 = MFMA16(ah0, bh0, acc00);
        acc00 = MFMA16(al0, bh0, acc00);
        acc00 = MFMA16(ah0, bl0, acc00);
        acc01 = MFMA16(ah0, bh1, acc01);
        acc01 = MFMA16(al0, bh1, acc01);
        acc01 = MFMA16(ah0, bl1, acc01);
        acc10 = MFMA16(ah1, bh0, acc10);
        acc10 = MFMA16(al1, bh0, acc10);
        acc10 = MFMA16(ah1, bl0, acc10);
        acc11 = MFMA16(ah1, bh1, acc11);
        acc11 = MFMA16(al1, bh1, acc11);
        acc11 = MFMA16(ah1, bl1, acc11);
        __syncthreads();
    }
    float* o = Fp + (size_t)kz * 512 * 1024;
    const int orow = (lane >> 4) * 4;
    #pragma unroll
    for (int r2 = 0; r2 < 4; ++r2) {
        o[(size_t)(m0+wm+orow+r2)*1024    + n0+wn+fr]    = acc00[r2];
        o[(size_t)(m0+wm+orow+r2)*1024    + n0+wn+16+fr] = acc01[r2];
        o[(size_t)(m0+wm+16+orow+r2)*1024 + n0+wn+fr]    = acc10[r2];
        o[(size_t)(m0+wm+16+orow+r2)*1024 + n0+wn+16+fr] = acc11[r2];
    }
}

// ---------------------------------------------------------------------------
// [4] Ea = exp2((p0+p1+bq)*2log2e)
// ---------------------------------------------------------------------------
__global__ __launch_bounds__(256) void exp_combine_kernel(
    const float* __restrict__ Ap, const float* __restrict__ bias,
    float* __restrict__ E)
{
    int i = blockIdx.x * 256 + threadIdx.x;
    float4 p0 = ((const float4*)Ap)[i];
    float4 p1 = ((const float4*)(Ap + (size_t)B_*TQ*NN))[i];
    float4 bb = ((const float4*)bias)[i & 255];
    float4 r;
    r.x = exp2f((p0.x + p1.x + bb.x) * K2F);
    r.y = exp2f((p0.y + p1.y + bb.y) * K2F);
    r.z = exp2f((p0.z + p1.z + bb.z) * K2F);
    r.w = exp2f((p0.w + p1.w + bb.w) * K2F);
    ((float4*)E)[i] = r;
}

// ---------------------------------------------------------------------------
// [5] scores v3: lane=k, wave-uniform q (scalar Ea/watt loads), paired-rcp.
// blockIdx.z = nh(16) x qh(2) -> 1024 blocks x 8 waves = 8192 waves.
// Per pair of n: A=1+ea0*ek0, B=1+ea1*ek1 ->
//   w0/A + w1/B = (w0*B + w1*A) * rcp(A*B)   [6 VALU + 1 rcp per 2 evals]
// ---------------------------------------------------------------------------
__global__ __launch_bounds__(512, 4) void score_sreg_kernel(
    const float* __restrict__ Ea,   // [512, 1024]
    const float* __restrict__ keys, // [2048, 1024]
    const float* __restrict__ watt, // [1024]
    float* __restrict__ Sp)         // [16][512][512]
{
    const int lane = threadIdx.x & 63;
    const int wid  = __builtin_amdgcn_readfirstlane(threadIdx.x >> 6);  // 0..7
    const int kt = blockIdx.x;          // 0..7
    const int b  = blockIdx.y;          // 0..3
    const int z  = blockIdx.z;          // 0..31
    const int nh = z & 15, qh = z >> 4;
    const int nbeg = nh * 64;
    const int krow = b*TK + kt*64 + lane;

    // per-lane: load + exp2 its keys chunk (64 values -> 64 VGPRs)
    float ek[64];
    const float* kp = keys + (size_t)krow*NN + nbeg;
    #pragma unroll
    for (int n4 = 0; n4 < 16; ++n4) {
        float4 kv = *(const float4*)(kp + n4*4);
        ek[n4*4+0] = exp2f(kv.x * K2F);
        ek[n4*4+1] = exp2f(kv.y * K2F);
        ek[n4*4+2] = exp2f(kv.z * K2F);
        ek[n4*4+3] = exp2f(kv.w * K2F);
    }
    const int q0 = b*TQ + qh*64 + wid*8;                       // 8 q rows/wave
    const float* __restrict__ wp  = watt + nbeg;               // uniform
    const float* __restrict__ eaq = Ea + (size_t)q0*NN + nbeg; // uniform
    float* op = Sp + ((size_t)nh*512 + q0)*TK + kt*64 + lane;

    for (int qi = 0; qi < 8; ++qi) {
        float s0 = 0.f, s1 = 0.f;
        #pragma unroll
        for (int n = 0; n < 64; n += 4) {
            float A  = fmaf(eaq[n+0], ek[n+0], 1.0f);
            float Bv = fmaf(eaq[n+1], ek[n+1], 1.0f);
            float C  = fmaf(eaq[n+2], ek[n+2], 1.0f);
            float D  = fmaf(eaq[n+3], ek[n+3], 1.0f);
            float num0 = fmaf(wp[n+0], Bv, wp[n+1] * A);
            float num1 = fmaf(wp[n+2], D,  wp[n+3] * C);
            s0 = fmaf(num0, __builtin_amdgcn_rcpf(A * Bv), s0);
            s1 = fmaf(num1, __builtin_amdgcn_rcpf(C * D),  s1);
        }
        *op = s0 + s1;
        eaq += NN;
        op += TK;
    }
}

// ---------------------------------------------------------------------------
// [6] softmax over k of (-2 * sum_{h<16} Sp[h]); writes P f32 + Ph/Pl
// ---------------------------------------------------------------------------
__global__ __launch_bounds__(256) void softmax_kernel(
    const float* __restrict__ Sp, float* __restrict__ P,
    ushort* __restrict__ Ph, ushort* __restrict__ Pl)
{
    const int lane = threadIdx.x & 63;
    const int wid  = threadIdx.x >> 6;
    const int row  = blockIdx.x * 4 + wid;
    const size_t S = (size_t)512*512;
    float v[8];
    float m = -3.4e38f;
    #pragma unroll
    for (int j = 0; j < 8; ++j) {
        int k = lane + j*64;
        float s = 0.f;
        #pragma unroll
        for (int h = 0; h < 16; ++h)
            s += Sp[h*S + (size_t)row*TK + k];
        v[j] = -2.0f * s;
        m = fmaxf(m, v[j]);
    }
    #pragma unroll
    for (int off = 32; off; off >>= 1) m = fmaxf(m, __shfl_xor(m, off, 64));
    float sum = 0.f;
    #pragma unroll
    for (int j = 0; j < 8; ++j) { v[j] = exp2f((v[j] - m) * LOG2EF); sum += v[j]; }
    #pragma unroll
    for (int off = 32; off; off >>= 1) sum += __shfl_xor(sum, off, 64);
    float inv = 1.0f / sum;
    #pragma unroll
    for (int j = 0; j < 8; ++j) {
        int k = lane + j*64;
        float pv = v[j] * inv;
        P[(size_t)row * TK + k] = pv;
        ushort h, l; split2(pv, h, l);
        Ph[(size_t)row * TK + k] = h;
        Pl[(size_t)row * TK + k] = l;
    }
}

// ---------------------------------------------------------------------------
// [8] Cx = Ep0+Ep1 -> hi/lo bf16
// ---------------------------------------------------------------------------
__global__ __launch_bounds__(256) void combine_cvt_kernel(
    const float* __restrict__ Ep, ushort* __restrict__ Ch, ushort* __restrict__ Cl)
{
    int i = blockIdx.x * 256 + threadIdx.x;
    float4 p0 = ((const float4*)Ep)[i];
    float4 p1 = ((const float4*)(Ep + (size_t)B_*TQ*VS))[i];
    float4 s = {p0.x+p1.x, p0.y+p1.y, p0.z+p1.z, p0.w+p1.w};
    ushort4 hh, ll;
    split2(s.x, hh.x, ll.x); split2(s.y, hh.y, ll.y);
    split2(s.z, hh.z, ll.z); split2(s.w, hh.w, ll.w);
    ((ushort4*)Ch)[i] = hh;
    ((ushort4*)Cl)[i] = ll;
}

// ---------------------------------------------------------------------------
// [10] out = tanh(sum Fp + bias)
// ---------------------------------------------------------------------------
__global__ __launch_bounds__(256) void tanh_combine_kernel(
    const float* __restrict__ Fp, const float* __restrict__ bias,
    float* __restrict__ out)
{
    int i = blockIdx.x * 256 + threadIdx.x;
    const size_t S = (size_t)B_*TQ*OS;
    float4 p0 = ((const float4*)Fp)[i];
    float4 p1 = ((const float4*)(Fp + S))[i];
    float4 p2 = ((const float4*)(Fp + 2*S))[i];
    float4 p3 = ((const float4*)(Fp + 3*S))[i];
    float4 bb = ((const float4*)bias)[i & 255];
    float4 r;
    r.x = tanhf(p0.x + p1.x + p2.x + p3.x + bb.x);
    r.y = tanhf(p0.y + p1.y + p2.y + p3.y + bb.y);
    r.z = tanhf(p0.z + p1.z + p2.z + p3.z + bb.z);
    r.w = tanhf(p0.w + p1.w + p2.w + p3.w + bb.w);
    ((float4*)out)[i] = r;
}

// ---------------------------------------------------------------------------
extern "C" void kernel_launch(void* const* d_in, const int* in_sizes, int n_in,
                              void* d_out, int out_size, void* d_ws, size_t ws_size,
                              hipStream_t stream)
{
    const float* query  = (const float*)d_in[0];
    const float* keys   = (const float*)d_in[1];
    const float* values = (const float*)d_in[2];
    const float* Wq     = (const float*)d_in[3];
    const float* bq     = (const float*)d_in[4];
    const float* watt   = (const float*)d_in[5];
    // d_in[6] = b_att: dropped (softmax shift-invariance)
    const float* Wout   = (const float*)d_in[7];
    const float* bout   = (const float*)d_in[8];

    float* out = (float*)d_out;                    // output 0 (524288 f32)
    float* P   = out + (size_t)B_*TQ*OS;           // output 1 (262144 f32)

    // ws: fully disjoint layout, 59 MB used (256 MiB available).
    char* base = (char*)d_ws;
    const size_t MB = 1u << 20;
    ushort* Qh  = (ushort*)(base +  0*MB);
    ushort* Ql  = (ushort*)(base +  1*MB);
    ushort* Wqh = (ushort*)(base +  2*MB);
    ushort* Wql = (ushort*)(base +  4*MB);
    ushort* Woh = (ushort*)(base +  6*MB);
    ushort* Wol = (ushort*)(base + 10*MB);
    ushort* Vth = (ushort*)(base + 14*MB);
    ushort* Vtl = (ushort*)(base + 18*MB);
    float*  Ap  = (float*) (base + 22*MB);   // [2][512][1024]
    float*  Ea  = (float*) (base + 26*MB);   // [512][1024]
    float*  Sp  = (float*) (base + 28*MB);   // [16][512][512] = 16 MB
    ushort* Ph  = (ushort*)(base + 44*MB);
    ushort* Pl  = (ushort*)(base + 44*MB + 512*1024);
    float*  Ep  = (float*) (base + 45*MB);   // [2][512][1024]
    ushort* Cxh = (ushort*)(base + 49*MB);
    ushort* Cxl = (ushort*)(base + 50*MB);
    float*  Fp  = (float*) (base + 51*MB);   // [4][512][1024]

    // [1] convert Q, Wq, Wout to hi/lo bf16
    cvt_fused_kernel<<<dim3(3584), dim3(256), 0, stream>>>(
        query, Wq, Wout, Qh, Ql, Wqh, Wql, Woh, Wol);
    // [2] V transpose + convert
    cvt_transpose_v_kernel<<<dim3(16, 8, 4), dim3(256), 0, stream>>>(values, Vth, Vtl);
    // [3] A-GEMM partials: Q @ Wq^T  (K=1024 split 2)
    mfma_nt_kernel<<<dim3(16, 8, 2), dim3(256), 0, stream>>>(
        Qh, Ql, Wqh, Wql, Ap, 1024, 1024, 1024, 512, 0);
    // [4] Ea = e^{2*(Aq+bq)}
    exp_combine_kernel<<<dim3(512), dim3(256), 0, stream>>>(Ap, bq, Ea);
    // [5] scores (paired-rcp, 2x wave count)
    score_sreg_kernel<<<dim3(8, 4, 32), dim3(512), 0, stream>>>(Ea, keys, watt, Sp);
    // [6] softmax -> P (output 1) + Ph/Pl
    softmax_kernel<<<dim3(128), dim3(256), 0, stream>>>(Sp, P, Ph, Pl);
    // [7] PV partials: P @ V (per-batch, K=512 split 2)
    mfma_nt_kernel<<<dim3(16, 8, 2), dim3(256), 0, stream>>>(
        Ph, Pl, Vth, Vtl, Ep, 512, 512, 1024, 256, VS*TK);
    // [8] Cx hi/lo
    combine_cvt_kernel<<<dim3(512), dim3(256), 0, stream>>>(Ep, Cxh, Cxl);
    // [9] out-GEMM partials (K=2048 split 4)
    mfma_out_kernel<<<dim3(16, 8, 4), dim3(256), 0, stream>>>(
        Qh, Ql, Cxh, Cxl, Woh, Wol, Fp);
    // [10] out = tanh(sum + bout)
    tanh_combine_kernel<<<dim3(512), dim3(256), 0, stream>>>(Fp, bout, out);
}